// Round 6
// baseline (302.466 us; speedup 1.0000x reference)
//
#include <hip/hip_runtime.h>
#include <math.h>

typedef __bf16 bf16x8 __attribute__((ext_vector_type(8)));
typedef float f32x4 __attribute__((ext_vector_type(4)));
typedef unsigned short ushort8 __attribute__((ext_vector_type(8)));
typedef unsigned short ushort4v __attribute__((ext_vector_type(4)));
typedef unsigned short u16;

#define DEVINL __device__ __forceinline__

DEVINL u16 f2bf(float f) {
    union { float f; unsigned u; } a; a.f = f;
    unsigned u = a.u;
    return (u16)((u + 0x7FFFu + ((u >> 16) & 1u)) >> 16);
}
DEVINL float bf2f(u16 h) { return __uint_as_float(((unsigned)h) << 16); }

DEVINL void gload_lds16(const void* g, void* l) {
    __builtin_amdgcn_global_load_lds(
        (__attribute__((address_space(1))) void*)(g),
        (__attribute__((address_space(3))) void*)(l),
        16, 0, 0);
}

// sched_group_barrier masks: VMEM=0x10, DS_READ=0x100, MFMA=0x8
#define SGB1(m, n) __builtin_amdgcn_sched_group_barrier(m, n, 0)
// staging phase: 4 gload_lds, 8 ds_read, 16 mfma -> (1 VMEM, 2 DS, 4 MFMA) x4
#define SCHED_STG do {                                                       \
    SGB1(0x10,1); SGB1(0x100,2); SGB1(0x8,4);                                \
    SGB1(0x10,1); SGB1(0x100,2); SGB1(0x8,4);                                \
    SGB1(0x10,1); SGB1(0x100,2); SGB1(0x8,4);                                \
    SGB1(0x10,1); SGB1(0x100,2); SGB1(0x8,4); } while (0)
// plain phase: 8 ds_read, 16 mfma -> (2 DS, 4 MFMA) x4
#define SCHED_PLN do {                                                       \
    SGB1(0x100,2); SGB1(0x8,4);                                              \
    SGB1(0x100,2); SGB1(0x8,4);                                              \
    SGB1(0x100,2); SGB1(0x8,4);                                              \
    SGB1(0x100,2); SGB1(0x8,4); } while (0)

// ---------------------------------------------------------------------------
// 256x256 GEMM, C = A @ B^T (B stored [N,K] row-major), bf16 in.
// BK=64 (2 slabs of 32), 8 waves (2M x 4N), per-wave output 128x64.
// Within-wave SW pipeline (two fragment register sets) + FORCED issue-order
// interleave via sched_group_barrier: each phase emits
// [VMEM, DS_READ x2, MFMA x4] x4 so a single wave feeds the LDS and matrix
// pipes from its own stream (2 waves/SIMD can't rely on cross-wave slip).
// Sync: 2 gates per K-tile (counted vmcnt(4) + s_barrier) - region
// boundaries for the scheduler, so vmcnt counts are unaffected by SGB.
// Swapped MFMA operands -> C^T fragment layout -> packed 8B/16B stores.
// EPI 0: C(bf16)=acc+bias[col]; EPI 1: C(bf16)=exp(acc*scale)+colsum->part;
// EPI 2: C(f32)=acc
// ---------------------------------------------------------------------------
template<int EPI>
__global__ __launch_bounds__(512, 2)
void gemm256(const u16* __restrict__ A, int lda, long sAz,
             const u16* __restrict__ B, int ldb, long sBz,
             void* __restrict__ Cv, int ldc, long sCz,
             const float* __restrict__ bias, float* __restrict__ part,
             float scale, int K)
{
    __shared__ u16 lds[65536];   // 128 KiB
    const int tid = threadIdx.x;
    const int tile_x = blockIdx.x, tile_y = blockIdx.y;
    const long bz = blockIdx.z;

    const u16* Ab = A + bz * sAz;
    const u16* Bb = B + bz * sBz;
    const int row0 = tile_x * 256, col0 = tile_y * 256;

    // staging: slab = [256 rows][32 cols] bf16 (64 B rows). row = tid>>2 (+128),
    // byte col = (tid&3)*16 pre-swizzled on the source side; LDS dest linear.
    const int sr = tid >> 2;
    const int csw = ((tid & 3) * 16) ^ (((sr >> 1) & 3) << 4);
    const u16* Ag = Ab + (long)(row0 + sr) * lda + (csw >> 1);
    const u16* Bg = Bb + (long)(col0 + sr) * ldb + (csw >> 1);
    const int dst0 = tid * 8;

    // fragment reads: lane reads row (+lane&15), 16B slot (lane>>4), swizzled.
    const int lane = tid & 63, wid = tid >> 6;
    const int wm = wid >> 2, wn = wid & 3;
    const int lane_r = lane & 15;
    const int rdcol = (((lane >> 4) * 16) ^ (((lane_r >> 1) & 3) << 4)) >> 1;
    const int arow0 = wm * 128 + lane_r;
    const int brow0 = wn * 64 + lane_r;

    const int NT = K >> 6;
    f32x4 acc[8][4] = {};
    bf16x8 aF0[4], bF0[4], aF1[4], bF1[4];

    auto issueA = [&](int t1, int s, int b) {
        const u16* g = Ag + (long)t1 * 64 + s * 32;
        u16* d = &lds[(b * 2 + s) * 8192 + dst0];
        gload_lds16(g, d);
        gload_lds16(g + (long)128 * lda, d + 4096);
    };
    auto issueB = [&](int t1, int s, int b) {
        const u16* g = Bg + (long)t1 * 64 + s * 32;
        u16* d = &lds[32768 + (b * 2 + s) * 8192 + dst0];
        gload_lds16(g, d);
        gload_lds16(g + (long)128 * ldb, d + 4096);
    };

#define READ_AB(bufv, s, h, SET)                                            \
    _Pragma("unroll")                                                       \
    for (int m = 0; m < 4; ++m)                                             \
        aF##SET[m] = *(const bf16x8*)&lds[((bufv) * 2 + (s)) * 8192 +       \
                         (arow0 + (h) * 64 + m * 16) * 32 + rdcol];         \
    _Pragma("unroll")                                                       \
    for (int n = 0; n < 4; ++n)                                             \
        bF##SET[n] = *(const bf16x8*)&lds[32768 + ((bufv) * 2 + (s)) * 8192 \
                         + (brow0 + n * 16) * 32 + rdcol];

#define MFMA16S(SET, h)                                                     \
    __builtin_amdgcn_s_setprio(1);                                          \
    _Pragma("unroll")                                                       \
    for (int m = 0; m < 4; ++m)                                             \
        _Pragma("unroll")                                                   \
        for (int n = 0; n < 4; ++n)                                         \
            acc[(h) * 4 + m][n] = __builtin_amdgcn_mfma_f32_16x16x32_bf16(  \
                bF##SET[n], aF##SET[m], acc[(h) * 4 + m][n], 0, 0, 0);      \
    __builtin_amdgcn_s_setprio(0);

#define GATE(n)                                                             \
    asm volatile("s_waitcnt vmcnt(" #n ")" ::: "memory");                   \
    __builtin_amdgcn_s_barrier();

    // prologue: K-tile 0 both slabs -> buf0; confirm s0
    issueA(0, 0, 0); issueB(0, 0, 0);
    issueA(0, 1, 0); issueB(0, 1, 0);
    GATE(4);
    READ_AB(0, 0, 0, 0);   // (s0,h0) -> set0

    for (int t = 0; t < NT - 1; ++t) {
        const int buf = t & 1, nbuf = buf ^ 1;
        // P1: stage s0(t+1); read (s0,h1)->set1; MFMA set0
        issueA(t + 1, 0, nbuf); issueB(t + 1, 0, nbuf);
        READ_AB(buf, 0, 1, 1);
        MFMA16S(0, 0);
        SCHED_STG;
        GATE(4);              // confirms s1(t)
        // P2: read (s1,h0)->set0; MFMA set1
        READ_AB(buf, 1, 0, 0);
        MFMA16S(1, 1);
        SCHED_PLN;
        // P3: stage s1(t+1); read (s1,h1)->set1; MFMA set0
        issueA(t + 1, 1, nbuf); issueB(t + 1, 1, nbuf);
        READ_AB(buf, 1, 1, 1);
        MFMA16S(0, 0);
        SCHED_STG;
        GATE(4);              // confirms s0(t+1)
        // P4: read (s0(t+1),h0)->set0; MFMA set1
        READ_AB(nbuf, 0, 0, 0);
        MFMA16S(1, 1);
        SCHED_PLN;
    }
    {   // peeled last K-tile (no staging)
        const int buf = (NT - 1) & 1;
        READ_AB(buf, 0, 1, 1);
        MFMA16S(0, 0);
        SCHED_PLN;
        GATE(0);              // confirms s1(last)
        READ_AB(buf, 1, 0, 0);
        MFMA16S(1, 1);
        READ_AB(buf, 1, 1, 1);
        MFMA16S(0, 0);
        MFMA16S(1, 1);
    }
#undef READ_AB
#undef MFMA16S
#undef GATE

    // epilogue (swapped layout): row = lane&15, col = (lane>>4)*4 + reg
    const int erow = lane & 15, ecol0 = (lane >> 4) * 4;
    float4 bias4[4];
    if constexpr (EPI == 0) {
#pragma unroll
        for (int nf = 0; nf < 4; ++nf)
            bias4[nf] = *(const float4*)&bias[col0 + wn * 64 + nf * 16 + ecol0];
    }
    f32x4 csum[4] = {};
#pragma unroll
    for (int mf = 0; mf < 8; ++mf) {
        const int gr = row0 + wm * 128 + mf * 16 + erow;
#pragma unroll
        for (int nf = 0; nf < 4; ++nf) {
            const int gc = col0 + wn * 64 + nf * 16 + ecol0;
            f32x4 v = acc[mf][nf];
            if constexpr (EPI == 0) {
                v[0] += bias4[nf].x; v[1] += bias4[nf].y;
                v[2] += bias4[nf].z; v[3] += bias4[nf].w;
                ushort4v o = { f2bf(v[0]), f2bf(v[1]), f2bf(v[2]), f2bf(v[3]) };
                *(ushort4v*)((u16*)Cv + bz * sCz + (long)gr * ldc + gc) = o;
            } else if constexpr (EPI == 1) {
                f32x4 e;
#pragma unroll
                for (int r = 0; r < 4; ++r) e[r] = __expf(v[r] * scale);
                csum[nf] += e;
                ushort4v o = { f2bf(e[0]), f2bf(e[1]), f2bf(e[2]), f2bf(e[3]) };
                *(ushort4v*)((u16*)Cv + bz * sCz + (long)gr * ldc + gc) = o;
            } else {
                *(float4*)((float*)Cv + bz * sCz + (long)gr * ldc + gc) =
                    make_float4(v[0], v[1], v[2], v[3]);
            }
        }
    }
    if constexpr (EPI == 1) {
#pragma unroll
        for (int nf = 0; nf < 4; ++nf)
#pragma unroll
            for (int r = 0; r < 4; ++r) {
                float s = csum[nf][r];
                s += __shfl_xor(s, 1);
                s += __shfl_xor(s, 2);
                s += __shfl_xor(s, 4);
                s += __shfl_xor(s, 8);
                csum[nf][r] = s;
            }
        if ((lane & 15) == 0) {
#pragma unroll
            for (int nf = 0; nf < 4; ++nf) {
                float* p = part + ((bz * 16 + (long)tile_x * 2 + wm) * 2048)
                         + col0 + wn * 64 + nf * 16 + ecol0;
                *(float4*)p = make_float4(csum[nf][0], csum[nf][1],
                                          csum[nf][2], csum[nf][3]);
            }
        }
    }
}

// ---------------------------------------------------------------------------
__global__ void cast_x_k(const float* __restrict__ x, u16* __restrict__ o)
{
    const int i = blockIdx.x * 256 + threadIdx.x;
    const float4* xv = (const float4*)x;
    const float4 a = xv[(long)i * 2], b = xv[(long)i * 2 + 1];
    ushort8 r;
    r[0] = f2bf(a.x); r[1] = f2bf(a.y); r[2] = f2bf(a.z); r[3] = f2bf(a.w);
    r[4] = f2bf(b.x); r[5] = f2bf(b.y); r[6] = f2bf(b.z); r[7] = f2bf(b.w);
    *(ushort8*)(o + (long)i * 8) = r;
}

__global__ void wt_k(const float* __restrict__ Wq, const float* __restrict__ Wk,
                     const float* __restrict__ Wv, u16* __restrict__ Wt)
{
    __shared__ float t[32][33];
    const int z = blockIdx.z;
    const float* W = (z == 0) ? Wq : ((z == 1) ? Wk : Wv);
    const int k0 = blockIdx.x * 32, n0 = blockIdx.y * 32;
    const int tx = threadIdx.x, ty = threadIdx.y;
#pragma unroll
    for (int j = 0; j < 32; j += 8)
        t[ty + j][tx] = W[(long)(k0 + ty + j) * 1024 + n0 + tx];
    __syncthreads();
#pragma unroll
    for (int j = 0; j < 32; j += 8)
        Wt[((long)z * 1024 + n0 + ty + j) * 1024 + k0 + tx] = f2bf(t[tx][ty + j]);
}

__global__ void bias_k(const float* __restrict__ bq, const float* __restrict__ bk,
                       const float* __restrict__ bv, float* __restrict__ bcat)
{
    const int i = blockIdx.x * 256 + threadIdx.x;
    bcat[i] = (i < 1024) ? bq[i] : ((i < 2048) ? bk[i - 1024] : bv[i - 2048]);
}

// rden[b][k] = 1 / sum_c part[b][c][k];  grid (8,8), block 256
__global__ void rcp_k(const float* __restrict__ part, float* __restrict__ rden)
{
    const int b = blockIdx.y;
    const int k = blockIdx.x * 256 + threadIdx.x;
    float s = 0.f;
#pragma unroll
    for (int c = 0; c < 16; ++c) s += part[((long)b * 16 + c) * 2048 + k];
    rden[b * 2048 + k] = 1.0f / s;
}

// Vt[b][d][k] = v[b][k][d] * rden[b][k]; grid (64,32,8), block (32,8)
__global__ void vt_k(const u16* __restrict__ qkv, const float* __restrict__ rden,
                     u16* __restrict__ Vt)
{
    __shared__ float t[32][33];
    const int b = blockIdx.z;
    const int k0 = blockIdx.x * 32, d0 = blockIdx.y * 32;
    const int tx = threadIdx.x, ty = threadIdx.y;
#pragma unroll
    for (int j = 0; j < 32; j += 8) {
        const int k = k0 + ty + j;
        t[ty + j][tx] = bf2f(qkv[((long)b * 2048 + k) * 3072 + 2048 + d0 + tx])
                        * rden[b * 2048 + k];
    }
    __syncthreads();
#pragma unroll
    for (int j = 0; j < 32; j += 8)
        Vt[((long)b * 1024 + d0 + ty + j) * 2048 + k0 + tx] = f2bf(t[tx][ty + j]);
}

// ---------------------------------------------------------------------------
extern "C" void kernel_launch(void* const* d_in, const int* in_sizes, int n_in,
                              void* d_out, int out_size, void* d_ws, size_t ws_size,
                              hipStream_t stream)
{
    const float* x  = (const float*)d_in[0];
    const float* Wq = (const float*)d_in[1];
    const float* bq = (const float*)d_in[2];
    const float* Wk = (const float*)d_in[3];
    const float* bk = (const float*)d_in[4];
    const float* Wv = (const float*)d_in[5];
    const float* bv = (const float*)d_in[6];

    char* ws = (char*)d_ws;
    u16*   qkv  = (u16*)(ws);                     // [16384][3072] bf16
    u16*   E    = (u16*)(ws + 100663296);         // [8][2048][2048] bf16
    u16*   Vt   = (u16*)(ws + 167772160);         // [8][1024][2048] bf16
    u16*   xb   = (u16*)(ws + 201326592);         // [16384][1024] bf16
    u16*   Wt   = (u16*)(ws + 234881024);         // [3072][1024] bf16
    float* bcat = (float*)(ws + 241172480);       // [3072] f32
    float* part = (float*)(ws + 241184768);       // [8][16][2048] f32
    float* rden = (float*)(ws + 243281920);       // [8][2048] f32

    const long sQKV = (long)2048 * 3072;
    const long sE   = (long)2048 * 2048;
    const long sVt  = (long)1024 * 2048;
    const long sO   = (long)2048 * 1024;

    cast_x_k<<<8192, 256, 0, stream>>>(x, xb);
    wt_k<<<dim3(32, 32, 3), dim3(32, 8), 0, stream>>>(Wq, Wk, Wv, Wt);
    bias_k<<<12, 256, 0, stream>>>(bq, bk, bv, bcat);
    // qkv = x @ Wt^T + bias   (M=16384, N=3072, K=1024)
    gemm256<0><<<dim3(64, 12, 1), 512, 0, stream>>>(
        xb, 1024, 0, Wt, 1024, 0, qkv, 3072, 0, bcat, nullptr, 0.f, 1024);
    // E = exp(scale * Q @ K^T), fused column-sum partials (M=N=2048, K=1024)
    gemm256<1><<<dim3(8, 8, 8), 512, 0, stream>>>(
        qkv, 3072, sQKV, qkv + 1024, 3072, sQKV, E, 2048, sE,
        nullptr, part, 0.03125f, 1024);
    rcp_k<<<dim3(8, 8), 256, 0, stream>>>(part, rden);
    vt_k<<<dim3(64, 32, 8), dim3(32, 8), 0, stream>>>(qkv, rden, Vt);
    // out = E @ Vt^T  (M=2048, N=1024, K=2048, fp32 out)
    gemm256<2><<<dim3(8, 4, 8), 512, 0, stream>>>(
        E, 2048, sE, Vt, 2048, sVt, d_out, 1024, sO,
        nullptr, nullptr, 1.f, 2048);
}